// Round 8
// baseline (111.599 us; speedup 1.0000x reference)
//
#include <hip/hip_runtime.h>
#include <hip/hip_fp16.h>

// B=4, S=512, D=256, UNITS=128. out: [B,S,D] fp32.
#define SEQ 512
#define DIM 256
#define UN  128
#define BSZ 2048                       // B*S
#define CSC 2.8853900817779268f        // 2*log2(e)

struct h4v { __half2 a, b; };          // 8B = 4 f16

static __device__ __forceinline__ unsigned short f2bf(float x) {  // RNE, x>0 finite
  unsigned u = __float_as_uint(x);
  u += 0x7FFF + ((u >> 16) & 1);
  return (unsigned short)(u >> 16);
}
static __device__ __forceinline__ float bf2f(unsigned short s) {
  return __uint_as_float((unsigned)s << 16);
}
// lane-broadcast from a preloaded register file: v_readlane_b32 (no memory, no waitcnt)
static __device__ __forceinline__ float rdlane(float v, int k) {
  return __int_as_float(__builtin_amdgcn_readlane(__float_as_int(v), k));
}

// ---- proj: Eq = exp2(CSC*(values@Wq)) [BSZ][UN] fp32,
//            Ev = bf16(exp2(CSC*(values@Wv)))^T [UN][BSZ],
//            Vf16 = f16(values) [BSZ][DIM]
__global__ __launch_bounds__(256) void proj_kernel(
    const float* __restrict__ values, const float* __restrict__ Wq,
    const float* __restrict__ Wv, float* __restrict__ Eq,
    unsigned short* __restrict__ Ev, __half* __restrict__ Vf16) {
  __shared__ float vsm[4 * DIM];
  const int t = threadIdx.x;
  const int r0 = blockIdx.x * 4;
  {
    const int row = t >> 6, c4 = (t & 63) * 4;
    const float4 v = *(const float4*)(values + (r0 + row) * DIM + c4);
    *(float4*)&vsm[row * DIM + c4] = v;
    __half2* vf = (__half2*)(Vf16 + (r0 + row) * DIM + c4);
    vf[0] = __floats2half2_rn(v.x, v.y);
    vf[1] = __floats2half2_rn(v.z, v.w);
  }
  __syncthreads();
  const int half = t >> 7, u = t & 127;
  const float* __restrict__ W = half ? Wv : Wq;
  float acc[4] = {0.f, 0.f, 0.f, 0.f};
  for (int d = 0; d < DIM; d += 4) {
    const float w0 = W[(d + 0) * UN + u], w1 = W[(d + 1) * UN + u];
    const float w2 = W[(d + 2) * UN + u], w3 = W[(d + 3) * UN + u];
#pragma unroll
    for (int k = 0; k < 4; ++k) {
      const float4 v = *(const float4*)&vsm[k * DIM + d];
      acc[k] = fmaf(v.x, w0, acc[k]);
      acc[k] = fmaf(v.y, w1, acc[k]);
      acc[k] = fmaf(v.z, w2, acc[k]);
      acc[k] = fmaf(v.w, w3, acc[k]);
    }
  }
  if (!half) {
#pragma unroll
    for (int k = 0; k < 4; ++k)
      Eq[(r0 + k) * UN + u] = __builtin_amdgcn_exp2f(acc[k] * CSC);
  } else {
    ushort4 o;
    o.x = f2bf(__builtin_amdgcn_exp2f(acc[0] * CSC));
    o.y = f2bf(__builtin_amdgcn_exp2f(acc[1] * CSC));
    o.z = f2bf(__builtin_amdgcn_exp2f(acc[2] * CSC));
    o.w = f2bf(__builtin_amdgcn_exp2f(acc[3] * CSC));
    *(ushort4*)(Ev + (size_t)u * BSZ + r0) = o;   // 8B aligned (r0%4==0)
  }
}

// ---- attn: block = (b, pair p), rows {p, S-1-p}; i <= 255 < 256 <= jhi always.
// tanh eval: d = fma(Eq, Ev, 1); term = Vw * rcp(d). All loop uniforms via readlane.
__global__ __launch_bounds__(256, 4) void attn_kernel(
    const __half* __restrict__ Vf16, const float* __restrict__ Eq,
    const unsigned short* __restrict__ Ev, const float* __restrict__ Vw,
    float* __restrict__ out) {
  __shared__ float sc[2 * SEQ];     // u-half-0 sdot -> probs. [lo | hi]; lo j>i zeroed
  __shared__ float scp[2 * SEQ];    // u-half-1 sdot partials
  __shared__ float part[8 * DIM];   // ctx partials: [wave g][2 rows][DIM]
  __shared__ float invs[2];

  const int t = threadIdx.x;
  const int lane = t & 63;
  const int b = blockIdx.x >> 8, p = blockIdx.x & 255;
  const int bS = b * SEQ;
  const int i = p;                  // low row: j in [0, i], i <= 255
  const int ihi = SEQ - 1 - p;      // high row: j in [0, jhi], jhi >= 256
  const int jhi = ihi;

  const float* __restrict__ eql = Eq + (size_t)(bS + i) * UN;
  const float* __restrict__ eqh = Eq + (size_t)(bS + ihi) * UN;
  const int u0 = (t >> 7) << 6;     // u-half of this thread

  // preload this wave's 64 loop-uniforms into lane registers (coalesced, once)
  const float qhv = eqh[u0 + lane];
  const float qlv = eql[u0 + lane];
  const float wv  = Vw[u0 + lane];

  // ---- phase A: thread owns j-quad (8B bf16 Ev load) x u-half; uniforms via readlane
  {
    const int qd = t & 127, jb = qd << 2;
    float* __restrict__ so = (t >> 7) ? scp : sc;
    const unsigned short* __restrict__ evp = Ev + (size_t)u0 * BSZ + bS + jb;
#define LDE(K) (*(const ushort4*)(evp + (size_t)(K) * BSZ))
    if ((t & 64) == 0) {            // waves 0,2: jb < 256 -> dual row
      float h0=0.f,h1=0.f,h2=0.f,h3=0.f,l0=0.f,l1=0.f,l2=0.f,l3=0.f;
      ushort4 e0 = LDE(0), e1 = LDE(1), e2 = LDE(2), e3 = LDE(3);
#define PRD(EC, KK) { \
      const float qh = rdlane(qhv, (KK)); \
      const float ql = rdlane(qlv, (KK)); \
      const float w  = rdlane(wv,  (KK)); \
      const float f0 = bf2f(EC.x), f1 = bf2f(EC.y), f2 = bf2f(EC.z), f3 = bf2f(EC.w); \
      h0 = fmaf(w, __builtin_amdgcn_rcpf(fmaf(qh, f0, 1.f)), h0); \
      h1 = fmaf(w, __builtin_amdgcn_rcpf(fmaf(qh, f1, 1.f)), h1); \
      h2 = fmaf(w, __builtin_amdgcn_rcpf(fmaf(qh, f2, 1.f)), h2); \
      h3 = fmaf(w, __builtin_amdgcn_rcpf(fmaf(qh, f3, 1.f)), h3); \
      l0 = fmaf(w, __builtin_amdgcn_rcpf(fmaf(ql, f0, 1.f)), l0); \
      l1 = fmaf(w, __builtin_amdgcn_rcpf(fmaf(ql, f1, 1.f)), l1); \
      l2 = fmaf(w, __builtin_amdgcn_rcpf(fmaf(ql, f2, 1.f)), l2); \
      l3 = fmaf(w, __builtin_amdgcn_rcpf(fmaf(ql, f3, 1.f)), l3); }
      for (int k = 0; k < 64; k += 4) {
        // prefetch overshoot (<= Ev row 131) lands in Vf16 ws region: valid memory
        ushort4 n;
        n = LDE(k + 4); PRD(e0, k + 0); e0 = n;
        n = LDE(k + 5); PRD(e1, k + 1); e1 = n;
        n = LDE(k + 6); PRD(e2, k + 2); e2 = n;
        n = LDE(k + 7); PRD(e3, k + 3); e3 = n;
      }
#undef PRD
      *(float4*)&so[SEQ + jb] = make_float4(h0, h1, h2, h3);
      *(float4*)&so[jb]       = make_float4(l0, l1, l2, l3);
    } else if (jb <= jhi) {         // waves 1,3: jb >= 256 -> hi only
      float h0=0.f,h1=0.f,h2=0.f,h3=0.f;
      ushort4 e0 = LDE(0), e1 = LDE(1), e2 = LDE(2), e3 = LDE(3);
#define PRS(EC, KK) { \
      const float qh = rdlane(qhv, (KK)); \
      const float w  = rdlane(wv,  (KK)); \
      h0 = fmaf(w, __builtin_amdgcn_rcpf(fmaf(qh, bf2f(EC.x), 1.f)), h0); \
      h1 = fmaf(w, __builtin_amdgcn_rcpf(fmaf(qh, bf2f(EC.y), 1.f)), h1); \
      h2 = fmaf(w, __builtin_amdgcn_rcpf(fmaf(qh, bf2f(EC.z), 1.f)), h2); \
      h3 = fmaf(w, __builtin_amdgcn_rcpf(fmaf(qh, bf2f(EC.w), 1.f)), h3); }
      for (int k = 0; k < 64; k += 4) {
        ushort4 n;
        n = LDE(k + 4); PRS(e0, k + 0); e0 = n;
        n = LDE(k + 5); PRS(e1, k + 1); e1 = n;
        n = LDE(k + 6); PRS(e2, k + 2); e2 = n;
        n = LDE(k + 7); PRS(e3, k + 3); e3 = n;
      }
#undef PRS
      *(float4*)&so[SEQ + jb] = make_float4(h0, h1, h2, h3);
    }
#undef LDE
  }
  __syncthreads();

  // ---- phase B: softmax; wave0 -> low row (zero-fill probs j in (i,256)), wave1 -> high
  {
    const int w = t >> 6, l = lane;
    if (w == 0) {
      float m = 1e30f;                            // min sdot == max score
      for (int j = l; j <= i; j += 64) m = fminf(m, sc[j] + scp[j]);
#pragma unroll
      for (int o = 32; o; o >>= 1) m = fminf(m, __shfl_xor(m, o));
      float sum = 0.f;
      for (int j = l; j < 256; j += 64) {
        if (j <= i) {
          const float pr = __builtin_amdgcn_exp2f((m - (sc[j] + scp[j])) * CSC);
          sc[j] = pr; sum += pr;
        } else {
          sc[j] = 0.f;                            // phase C loop-1 reads these
        }
      }
#pragma unroll
      for (int o = 32; o; o >>= 1) sum += __shfl_xor(sum, o);
      if (l == 0) invs[0] = __builtin_amdgcn_rcpf(sum);
    } else if (w == 1) {
      float m = 1e30f;
      for (int j = l; j <= jhi; j += 64) m = fminf(m, sc[SEQ + j] + scp[SEQ + j]);
#pragma unroll
      for (int o = 32; o; o >>= 1) m = fminf(m, __shfl_xor(m, o));
      float sum = 0.f;
      for (int j = l; j <= jhi; j += 64) {
        const float pr = __builtin_amdgcn_exp2f((m - (sc[SEQ + j] + scp[SEQ + j])) * CSC);
        sc[SEQ + j] = pr; sum += pr;
      }
#pragma unroll
      for (int o = 32; o; o >>= 1) sum += __shfl_xor(sum, o);
      if (l == 0) invs[1] = __builtin_amdgcn_rcpf(sum);
    }
  }
  __syncthreads();

  // ---- phase C: 4 d/lane (full DIM per wave); wave g takes j === g (mod 4);
  //      probs preloaded to lane registers, fetched via readlane (no LDS in loop)
  {
    const int g = t >> 6;
    const int d4 = lane << 2;
    const float plo0 = sc[g + (lane << 2)];              // lane k <-> j = g+4k (<256)
    const float phi0 = sc[SEQ + g + (lane << 2)];
    const float phi1 = sc[SEQ + 256 + g + (lane << 2)];  // j = 256+g+4k
    float a0=0.f,a1=0.f,a2=0.f,a3=0.f, c0=0.f,c1=0.f,c2=0.f,c3=0.f;
    const __half* __restrict__ vb = Vf16 + (size_t)bS * DIM + d4;
    h4v vc = *(const h4v*)(vb + g * DIM);
    // loop 1: k=0..63, j = g+4k < 256 <= jhi: dual row, branch-free (lo probs zeroed)
#pragma unroll 8
    for (int k = 0; k < 64; ++k) {
      const h4v vn = *(const h4v*)(vb + (size_t)(g + 4 * k + 4) * DIM);  // <=row 259: valid
      const float pl = rdlane(plo0, k), ph = rdlane(phi0, k);
      const float2 f01 = __half22float2(vc.a), f23 = __half22float2(vc.b);
      a0 = fmaf(pl, f01.x, a0); a1 = fmaf(pl, f01.y, a1);
      a2 = fmaf(pl, f23.x, a2); a3 = fmaf(pl, f23.y, a3);
      c0 = fmaf(ph, f01.x, c0); c1 = fmaf(ph, f01.y, c1);
      c2 = fmaf(ph, f23.x, c2); c3 = fmaf(ph, f23.y, c3);
      vc = vn;
    }
    // loop 2: j = g+256 .. jhi: high row only (i <= 255 < j)
    int k2 = 0;
#pragma unroll 4
    for (int j = g + 256; j <= jhi; j += 4, ++k2) {
      const int jn = (j + 4 <= jhi) ? j + 4 : jhi;
      const h4v vn = *(const h4v*)(vb + (size_t)jn * DIM);
      const float ph = rdlane(phi1, k2);
      const float2 f01 = __half22float2(vc.a), f23 = __half22float2(vc.b);
      c0 = fmaf(ph, f01.x, c0); c1 = fmaf(ph, f01.y, c1);
      c2 = fmaf(ph, f23.x, c2); c3 = fmaf(ph, f23.y, c3);
      vc = vn;
    }
    *(float4*)&part[(g * 2 + 0) * DIM + d4] = make_float4(a0, a1, a2, a3);
    *(float4*)&part[(g * 2 + 1) * DIM + d4] = make_float4(c0, c1, c2, c3);
  }
  __syncthreads();

  // ---- epilogue ----
  {
    const float olo = (part[0 * DIM + t] + part[2 * DIM + t] +
                       part[4 * DIM + t] + part[6 * DIM + t]) * invs[0];
    const float ohi = (part[1 * DIM + t] + part[3 * DIM + t] +
                       part[5 * DIM + t] + part[7 * DIM + t]) * invs[1];
    out[(size_t)(bS + i) * DIM + t] = olo;
    out[(size_t)(bS + ihi) * DIM + t] = ohi;
  }
}

extern "C" void kernel_launch(void* const* d_in, const int* in_sizes, int n_in,
                              void* d_out, int out_size, void* d_ws, size_t ws_size,
                              hipStream_t stream) {
  const float* values = (const float*)d_in[0];
  const float* Wq     = (const float*)d_in[1];
  const float* Wv     = (const float*)d_in[2];
  const float* Vw     = (const float*)d_in[3];
  float* out = (float*)d_out;
  float* Eq = (float*)d_ws;                            // [BSZ][UN] fp32, 1 MB
  unsigned short* Ev = (unsigned short*)(Eq + (size_t)BSZ * UN);  // [UN][BSZ] bf16, 512 KB
  __half* Vf16 = (__half*)(Ev + (size_t)UN * BSZ);     // [BSZ][DIM] f16, 1 MB (A-prefetch overshoot target)
  proj_kernel<<<dim3(BSZ / 4), 256, 0, stream>>>(values, Wq, Wv, Eq, Ev, Vf16);
  attn_kernel<<<dim3(4 * 256), 256, 0, stream>>>(Vf16, Eq, Ev, Vw, out);
}